// Round 11
// baseline (239.710 us; speedup 1.0000x reference)
//
#include <hip/hip_runtime.h>
#include <math.h>

// Problem constants
#define B_ 4
#define L_ 2048
#define D_ 256
#define H_ 8
#define DH_ 32
#define NH_ 32           // B*H
#define U_ 40
#define LD_ 524288       // L_*D_ floats per batch
#define NCH_ 16          // attention L-chunks

typedef __attribute__((ext_vector_type(8))) short short8;
typedef __attribute__((ext_vector_type(4))) float floatx4;

static __device__ __forceinline__ unsigned long long ullmin_(unsigned long long a, unsigned long long b) {
    return a < b ? a : b;
}
static __device__ __forceinline__ unsigned short f2bf_rne(float x) {
    unsigned u = __float_as_uint(x);
    unsigned r = u + 0x7FFFu + ((u >> 16) & 1u);
    return (unsigned short)(r >> 16);
}
static __device__ __forceinline__ float bf2f(unsigned short h) {
    return __uint_as_float(((unsigned)h) << 16);
}

// ---------------------------------------------------------------------------
// W pre-split v2 (R9 proven): fp32 W[col][k] -> THREE bf16 planes in
// LANE-MAJOR fragment tiles (staging + ds_read conflict-free).
// ---------------------------------------------------------------------------
__global__ __launch_bounds__(256) void wsplit(const float* __restrict__ Wq,
                                              const float* __restrict__ Wk,
                                              const float* __restrict__ Wv,
                                              unsigned short* __restrict__ Whs,
                                              unsigned short* __restrict__ Wms,
                                              unsigned short* __restrict__ Wls) {
    const int g = blockIdx.x * 256 + threadIdx.x;   // 0..49151
    const int mat = g >> 14;                         // 3 mats * 16384 float4
    const int rem = g & 16383;
    const int col = rem >> 6;                        // 0..255
    const int k4 = rem & 63;                         // 0..63 (k = k4*4)
    const float* W = (mat == 0) ? Wq : (mat == 1) ? Wk : Wv;
    const float4 x = *(const float4*)(W + (size_t)col * 256 + k4 * 4);
    float xs[4] = {x.x, x.y, x.z, x.w};
    unsigned short hv[4], mv[4], lv[4];
#pragma unroll
    for (int j = 0; j < 4; ++j) {
        hv[j] = f2bf_rne(xs[j]);
        const float e1 = xs[j] - bf2f(hv[j]);
        mv[j] = f2bf_rne(e1);
        const float e2 = e1 - bf2f(mv[j]);
        lv[j] = f2bf_rne(e2);
    }
    const int colblk = col >> 6, c64 = col & 63;
    const int jt = c64 >> 4, cin = c64 & 15;
    const int kt = k4 >> 3, g8 = k4 & 7;
    const int quad = g8 >> 1, half = g8 & 1;
    const size_t o = ((((size_t)mat * 4 + colblk) * 8 + kt) << 11) +
                     jt * 512 + (quad * 16 + cin) * 8 + half * 4;
    *(ushort4*)(Whs + o) = make_ushort4(hv[0], hv[1], hv[2], hv[3]);
    *(ushort4*)(Wms + o) = make_ushort4(mv[0], mv[1], mv[2], mv[3]);
    *(ushort4*)(Wls + o) = make_ushort4(lv[0], lv[1], lv[2], lv[3]);
}

// ---------------------------------------------------------------------------
// X pre-split (NEW): fp32 X[row][k] (q,k,v stacked) -> bf16 A-planes in the
// A-fragment LANE-MAJOR layout: tile = 16 rows x 32 k (rowtile, kt), lane =
// quad*16 + (row&15) holds k = kt*32 + quad*8 .. +8; short index
//   ((mat*512 + rowtile)*8 + kt)*512 + lane*8 + half*4.
// Same RNE split as the old in-GEMM conversion -> values bit-identical.
// V (mat 2) skips the l-plane. ~56 MB traffic, HBM-bound (~9us).
// R10 profile: gemm_proj was A-conversion-VALU-bound (VALUBusy 35.8%) with
// 2x redundant conversion -- this pass removes all of it from the GEMM.
// ---------------------------------------------------------------------------
__global__ __launch_bounds__(256) void xsplit(const float* __restrict__ q,
                                              const float* __restrict__ k,
                                              const float* __restrict__ v,
                                              unsigned short* __restrict__ Xh,
                                              unsigned short* __restrict__ Xm,
                                              unsigned short* __restrict__ Xl) {
    const int g = blockIdx.x * 256 + threadIdx.x;   // 0..1572863
    const int mat = g >> 19;                         // 3 mats * 524288 float4
    const int rem = g & 524287;
    const int row = rem >> 6;                        // 0..8191
    const int k4 = rem & 63;                         // 0..63
    const float* X = (mat == 0) ? q : (mat == 1) ? k : v;
    const float4 x = *(const float4*)(X + (size_t)row * 256 + k4 * 4);
    float xs[4] = {x.x, x.y, x.z, x.w};
    unsigned short hv[4], mv[4], lv[4];
#pragma unroll
    for (int j = 0; j < 4; ++j) {
        hv[j] = f2bf_rne(xs[j]);
        const float e1 = xs[j] - bf2f(hv[j]);
        mv[j] = f2bf_rne(e1);
        const float e2 = e1 - bf2f(mv[j]);
        lv[j] = f2bf_rne(e2);
    }
    const int rowtile = row >> 4, rin = row & 15;
    const int kt = k4 >> 3, g8 = k4 & 7;
    const int quad = g8 >> 1, half = g8 & 1;
    const size_t o = ((((size_t)mat * 512 + rowtile) * 8 + kt) << 9) +
                     (quad * 16 + rin) * 8 + half * 4;
    *(ushort4*)(Xh + o) = make_ushort4(hv[0], hv[1], hv[2], hv[3]);
    *(ushort4*)(Xm + o) = make_ushort4(mv[0], mv[1], mv[2], mv[3]);
    if (mat < 2)
        *(ushort4*)(Xl + o) = make_ushort4(lv[0], lv[1], lv[2], lv[3]);
}

// ---------------------------------------------------------------------------
// Batched projection GEMM v6: pure load+MFMA. A fragments load directly from
// the pre-split X planes (3 contiguous 1KB short8 loads per wave per kt,
// prefetched one kt ahead -- T14); B staged in LDS double-buffered (R9
// proven). ZERO conversion VALU in the loop. MFMA order/operands verbatim
// from R9/R10 -> qp,kp,vp bit-identical (selection safety).
// Grid (128,2,3), block = 64 rows x 128 cols, 4 waves, 48KB LDS.
// ---------------------------------------------------------------------------
__global__ __launch_bounds__(256) void gemm_proj(const unsigned short* __restrict__ Xh,
                                                 const unsigned short* __restrict__ Xm,
                                                 const unsigned short* __restrict__ Xl,
                                                 const unsigned short* __restrict__ Whs,
                                                 const unsigned short* __restrict__ Wms,
                                                 const unsigned short* __restrict__ Wls,
                                                 const float* __restrict__ bq,
                                                 const float* __restrict__ bk,
                                                 const float* __restrict__ bv,
                                                 float* __restrict__ qp,
                                                 float* __restrict__ kp,
                                                 float* __restrict__ vp) {
    const int mat = blockIdx.z;
    const float* bias = (mat == 0) ? bq : (mat == 1) ? bk : bv;
    float* Y = (mat == 0) ? qp : (mat == 1) ? kp : vp;
    const bool vmat = (mat == 2);

    const int t = threadIdx.x;
    const int w = t >> 6, lane = t & 63;
    const int lq = lane & 15, quad = lane >> 4;
    const int rowBase = blockIdx.x * 64 + w * 16;   // wave owns 16 rows
    const int colBase = blockIdx.y * 128;           // block owns 128 cols
    const int nseg = vmat ? 16 : 24;                // V skips the l-plane
    const int rowtile = blockIdx.x * 4 + w;

    __shared__ unsigned short Bls[2][12288];        // 48 KB

    floatx4 acc[8];
#pragma unroll
    for (int nt2 = 0; nt2 < 8; ++nt2) acc[nt2] = (floatx4){0.f, 0.f, 0.f, 0.f};

    auto gsrc = [&](int s, int kt) -> const unsigned short* {
        const int p = s >> 3, rm = s & 7, chunk = rm >> 2, jj = rm & 3;
        const unsigned short* Wp = (p == 0) ? Whs : (p == 1) ? Wms : Wls;
        return Wp + (((((size_t)mat * 4 + ((blockIdx.y << 1) | chunk)) * 8 + kt) << 11) +
                     jj * 512 + lane * 8);
    };
    auto abase = [&](int kt) -> size_t {
        return ((((size_t)mat * 512 + rowtile) * 8 + kt) << 9) + lane * 8;
    };

    // prologue: stage B(kt=0) into buf 0; load A(kt=0)
#pragma unroll
    for (int n = 0; n < 6; ++n) {
        const int s = w + n * 4;
        if (s < nseg)
            *(short8*)&Bls[0][s * 512 + lane * 8] = *(const short8*)gsrc(s, 0);
    }
    short8 Ah = *(const short8*)(Xh + abase(0));
    short8 Am = *(const short8*)(Xm + abase(0));
    short8 Al;
    if (!vmat) Al = *(const short8*)(Xl + abase(0));
    __syncthreads();

    for (int kt = 0; kt < 8; ++kt) {
        const int buf = kt & 1;

        // T14 async-split: issue next tile's global loads EARLY
        short8 nAh, nAm, nAl;
        short8 stg[6];
        if (kt < 7) {
            nAh = *(const short8*)(Xh + abase(kt + 1));
            nAm = *(const short8*)(Xm + abase(kt + 1));
            if (!vmat) nAl = *(const short8*)(Xl + abase(kt + 1));
#pragma unroll
            for (int n = 0; n < 6; ++n) {
                const int s = w + n * 4;
                if (s < nseg) stg[n] = *(const short8*)gsrc(s, kt + 1);
            }
        }

        // 8 nt-tiles from LDS: conflict-free ds_read_b128, 6 (or 3) MFMAs
        const unsigned short* Bb = Bls[buf];
#pragma unroll
        for (int nt2 = 0; nt2 < 8; ++nt2) {
            const int boff = ((nt2 >> 2) << 11) + ((nt2 & 3) << 9) + lane * 8;
            const short8 Bh = *(const short8*)&Bb[boff];
            const short8 Bm = *(const short8*)&Bb[4096 + boff];
            floatx4 a = acc[nt2];
            if (!vmat) {
                const short8 Bl = *(const short8*)&Bb[8192 + boff];
                a = __builtin_amdgcn_mfma_f32_16x16x32_bf16(Am, Bm, a, 0, 0, 0);
                a = __builtin_amdgcn_mfma_f32_16x16x32_bf16(Ah, Bl, a, 0, 0, 0);
                a = __builtin_amdgcn_mfma_f32_16x16x32_bf16(Al, Bh, a, 0, 0, 0);
                a = __builtin_amdgcn_mfma_f32_16x16x32_bf16(Ah, Bm, a, 0, 0, 0);
                a = __builtin_amdgcn_mfma_f32_16x16x32_bf16(Am, Bh, a, 0, 0, 0);
                a = __builtin_amdgcn_mfma_f32_16x16x32_bf16(Ah, Bh, a, 0, 0, 0);
            } else {
                a = __builtin_amdgcn_mfma_f32_16x16x32_bf16(Ah, Bm, a, 0, 0, 0);
                a = __builtin_amdgcn_mfma_f32_16x16x32_bf16(Am, Bh, a, 0, 0, 0);
                a = __builtin_amdgcn_mfma_f32_16x16x32_bf16(Ah, Bh, a, 0, 0, 0);
            }
            acc[nt2] = a;
        }

        // write staged B regs to the other buffer; roll A
#pragma unroll
        for (int n = 0; n < 6; ++n) {
            const int s = w + n * 4;
            if (kt < 7 && s < nseg)
                *(short8*)&Bls[buf ^ 1][s * 512 + lane * 8] = stg[n];
        }
        Ah = nAh; Am = nAm;
        if (!vmat) Al = nAl;
        __syncthreads();
    }

#pragma unroll
    for (int nt2 = 0; nt2 < 8; ++nt2) {
        const int c = colBase + nt2 * 16 + lq;
        const float bv_ = bias[c];
#pragma unroll
        for (int r = 0; r < 4; ++r) {
            const int mr = rowBase + quad * 4 + r;
            Y[(size_t)mr * 256 + c] = acc[nt2][r] + bv_;
        }
    }
}

// ---------------------------------------------------------------------------
// kconv + ksum v2 (R10): XCD-clustered swizzle; per-block work verbatim.
// ---------------------------------------------------------------------------
__global__ __launch_bounds__(256) void kconv_ksum(const float* __restrict__ kp,
                                                  const int* __restrict__ idx,
                                                  unsigned short* __restrict__ Khi,
                                                  unsigned short* __restrict__ Klo,
                                                  float* __restrict__ Ksum32) {
    const int blk = ((blockIdx.x & 7) << 7) + (blockIdx.x >> 3);  // XCD swizzle
    const int i = blk >> 5, uc = blk & 31;
    const int b = i >> 3, h = i & 7;
    const int t = threadIdx.x;
    const int dq = (t & 7) * 4;
    const int ur = t >> 3;  // 0..31

    __shared__ float part[32][36];
    float ksum[4] = {0.f, 0.f, 0.f, 0.f};

#pragma unroll
    for (int p = 0; p < 2; ++p) {
        int u = uc * 64 + p * 32 + ur;
        const float4 x = *(const float4*)(kp + (size_t)b * LD_ + (size_t)idx[u] * D_ + h * DH_ + dq);
        float xs[4] = {x.x, x.y, x.z, x.w};
        unsigned short hv[4], lv[4];
#pragma unroll
        for (int j = 0; j < 4; ++j) {
            ksum[j] += xs[j];
            hv[j] = f2bf_rne(xs[j]);
            lv[j] = f2bf_rne(xs[j] - bf2f(hv[j]));
        }
        size_t o = ((size_t)i * 2048 + u) * 32 + dq;
        *(ushort4*)(Khi + o) = make_ushort4(hv[0], hv[1], hv[2], hv[3]);
        *(ushort4*)(Klo + o) = make_ushort4(lv[0], lv[1], lv[2], lv[3]);
    }
#pragma unroll
    for (int j = 0; j < 4; ++j) part[ur][dq + j] = ksum[j];
    __syncthreads();
    if (t < 32) {
        float s = 0.f;
#pragma unroll 8
        for (int u2 = 0; u2 < 32; ++u2) s += part[u2][t];
        Ksum32[(size_t)blk * 32 + t] = s;
    }
}

// ---------------------------------------------------------------------------
// Approx M-sweep v2 (R10): lt=8, XCD-clustered swizzle; Mv/Qmean
// bit-identical chain.
// ---------------------------------------------------------------------------
__global__ __launch_bounds__(256) void mpart_mfma(const float* __restrict__ qp,
                                                  const unsigned short* __restrict__ Khi,
                                                  const unsigned short* __restrict__ Klo,
                                                  const float* __restrict__ Ksum32,
                                                  float* __restrict__ Mv,
                                                  float* __restrict__ Qmean) {
    const int lb = ((blockIdx.x & 7) << 6) + (blockIdx.x >> 3);  // XCD swizzle, 512 blocks
    const int i = lb >> 4;      // 32
    const int lg = lb & 15;     // 16 groups of 128 rows
    const int t = threadIdx.x;
    const int w = t >> 6;
    const int lane = t & 63;
    const int lq = lane & 15;
    const int quad = lane >> 4;

    __shared__ float ssum[32];
    __shared__ float red[4][128];
    if (t < 32) {
        float s = 0.f;
#pragma unroll 8
        for (int uc = 0; uc < 32; ++uc) s += Ksum32[((size_t)i * 32 + uc) * 32 + t];
        ssum[t] = s;
    }

    short8 Ah[8], Al[8];
#pragma unroll
    for (int lt = 0; lt < 8; ++lt) {
        const int l = lg * 128 + lt * 16 + lq;
        const float* qrow = qp + ((size_t)i * 2048 + l) * 32 + quad * 8;
        float4 x0 = *(const float4*)(qrow);
        float4 x1 = *(const float4*)(qrow + 4);
        float xs[8] = {x0.x, x0.y, x0.z, x0.w, x1.x, x1.y, x1.z, x1.w};
#pragma unroll
        for (int j = 0; j < 8; ++j) {
            unsigned short h = f2bf_rne(xs[j]);
            unsigned short lo = f2bf_rne(xs[j] - bf2f(h));
            Ah[lt][j] = (short)h;
            Al[lt][j] = (short)lo;
        }
    }

    floatx4 rmax[8];
#pragma unroll
    for (int lt = 0; lt < 8; ++lt)
        rmax[lt] = (floatx4){-INFINITY, -INFINITY, -INFINITY, -INFINITY};

    const size_t kfrag = ((size_t)i * 2048 + w * 512 + lq) * 32 + quad * 8;
    const unsigned short* ph = Khi + kfrag;
    const unsigned short* pl = Klo + kfrag;
#pragma unroll 2
    for (int s = 0; s < 32; ++s) {
        short8 Bh = *(const short8*)(ph + (size_t)s * 512);
        short8 Bl = *(const short8*)(pl + (size_t)s * 512);
#pragma unroll
        for (int lt = 0; lt < 8; ++lt) {
            floatx4 acc = (floatx4){0.f, 0.f, 0.f, 0.f};
            acc = __builtin_amdgcn_mfma_f32_16x16x32_bf16(Al[lt], Bh, acc, 0, 0, 0);
            acc = __builtin_amdgcn_mfma_f32_16x16x32_bf16(Ah[lt], Bl, acc, 0, 0, 0);
            acc = __builtin_amdgcn_mfma_f32_16x16x32_bf16(Ah[lt], Bh, acc, 0, 0, 0);
#pragma unroll
            for (int r = 0; r < 4; ++r) rmax[lt][r] = fmaxf(rmax[lt][r], acc[r]);
        }
    }

#pragma unroll
    for (int lt = 0; lt < 8; ++lt)
#pragma unroll
        for (int r = 0; r < 4; ++r) {
            float v = rmax[lt][r];
#pragma unroll
            for (int off = 1; off < 16; off <<= 1)
                v = fmaxf(v, __shfl_xor(v, off, 64));
            rmax[lt][r] = v;
        }
    if (lq == 0) {
#pragma unroll
        for (int lt = 0; lt < 8; ++lt)
#pragma unroll
            for (int r = 0; r < 4; ++r)
                red[w][lt * 16 + quad * 4 + r] = rmax[lt][r];
    }
    __syncthreads();
    if (t < 128) {
        const int l = lg * 128 + t;
        float m = fmaxf(fmaxf(red[0][t], red[1][t]), fmaxf(red[2][t], red[3][t]));
        const float4* q4 = (const float4*)(qp + ((size_t)i * 2048 + l) * 32);
        const float4* s4 = (const float4*)ssum;
        float qs = 0.f;
#pragma unroll
        for (int z = 0; z < 8; ++z) {
            float4 a = q4[z];
            float4 c = s4[z];
            qs = fmaf(a.x, c.x, qs);
            qs = fmaf(a.y, c.y, qs);
            qs = fmaf(a.z, c.z, qs);
            qs = fmaf(a.w, c.w, qs);
        }
        const float qm = qs * (1.0f / 2048.0f);
        Qmean[(size_t)i * 2048 + l] = qm;
        Mv[(size_t)i * 2048 + l] = m - qm;
    }
}

// ---------------------------------------------------------------------------
// FAST bottom-64: 4-level byte radix-select (R5 proven). Grid 32 x 256.
// ---------------------------------------------------------------------------
__global__ __launch_bounds__(256) void topk64_fast(const float* __restrict__ Mv,
                                                   int* __restrict__ candIdx) {
    const int i = blockIdx.x;
    const int t = threadIdx.x;
    const int w = t >> 6, lane = t & 63;

    __shared__ unsigned hist[256];
    __shared__ unsigned sh_prefix, sh_selBelow;
    __shared__ unsigned cnt;
    __shared__ int candLds[64];
    __shared__ unsigned long long wred[4];

    unsigned v[8];
#pragma unroll
    for (int j = 0; j < 8; ++j) {
        const unsigned u = __float_as_uint(Mv[(size_t)i * 2048 + t + 256 * j]);
        v[j] = (u & 0x80000000u) ? ~u : (u | 0x80000000u);  // monotone map
    }

    if (t == 0) { sh_prefix = 0u; sh_selBelow = 0u; cnt = 0u; }

    for (int level = 0; level < 4; ++level) {
        const int shift = 24 - 8 * level;
        __syncthreads();                       // publish sh_* ; prev scan done
        const unsigned prefHi = sh_prefix;
        const unsigned selB = sh_selBelow;
        const unsigned mask = (level == 0) ? 0u : (0xFFFFFFFFu << (shift + 8));
        hist[t] = 0u;
        __syncthreads();
#pragma unroll
        for (int j = 0; j < 8; ++j)
            if ((v[j] & mask) == prefHi)
                atomicAdd(&hist[(v[j] >> shift) & 255u], 1u);
        __syncthreads();
        if (t < 64) {
            const unsigned c0 = hist[t * 4 + 0], c1 = hist[t * 4 + 1];
            const unsigned c2 = hist[t * 4 + 2], c3 = hist[t * 4 + 3];
            const unsigned i0 = c0, i1 = c0 + c1, i2 = i1 + c2, i3 = i2 + c3;
            unsigned x = i3;
#pragma unroll
            for (int off = 1; off < 64; off <<= 1) {
                const unsigned y = __shfl_up(x, off, 64);
                if (t >= off) x += y;
            }
            const unsigned excl = x - i3;          // wave-exclusive sum
            const unsigned r = 64u - selB;         // still needed, >= 1
            const unsigned long long ball = __ballot(x >= r);
            const int flane = __ffsll(ball) - 1;   // invariant: exists
            if (t == flane) {
                unsigned k, ce;
                if (excl + i0 >= r)      { k = 0u; ce = excl; }
                else if (excl + i1 >= r) { k = 1u; ce = excl + i0; }
                else if (excl + i2 >= r) { k = 2u; ce = excl + i1; }
                else                     { k = 3u; ce = excl + i2; }
                sh_prefix = prefHi | (((unsigned)t * 4u + k) << shift);
                sh_selBelow = selB + ce;
            }
        }
    }
    __syncthreads();
    const unsigned thr = sh_prefix;            // exact 64th-smallest value
    const unsigned selB = sh_selBelow;         // #keys strictly below thr (<64)
    const int rem = 64 - (int)selB;            // >= 1, filled from ties at thr

    unsigned long long keys[8];
#pragma unroll
    for (int j = 0; j < 8; ++j) {
        const int l = t + 256 * j;
        if (v[j] < thr) {
            const unsigned p = atomicAdd(&cnt, 1u);
            candLds[p] = l;
            keys[j] = ~0ULL;
        } else if (v[j] == thr) {
            keys[j] = ((unsigned long long)v[j] << 32) | (unsigned)l;
        } else {
            keys[j] = ~0ULL;
        }
    }
    __syncthreads();

    for (int it = 0; it < rem; ++it) {
        unsigned long long best = keys[0];
#pragma unroll
        for (int j = 1; j < 8; ++j) best = ullmin_(best, keys[j]);
#pragma unroll
        for (int off = 1; off < 64; off <<= 1)
            best = ullmin_(best, __shfl_xor(best, off, 64));
        if (lane == 0) wred[w] = best;
        __syncthreads();
        const unsigned long long m = ullmin_(ullmin_(wred[0], wred[1]), ullmin_(wred[2], wred[3]));
        if (t == 0) candLds[selB + it] = (int)(m & 0xffffffffu);
#pragma unroll
        for (int j = 0; j < 8; ++j)
            if (keys[j] == m) keys[j] = ~0ULL;
        __syncthreads();
    }

    if (t < 64) candIdx[i * 64 + t] = candLds[t];
}

// ---------------------------------------------------------------------------
// Exact fp32 refine: grid 256 = i*8 + chunk (256 u each). (verbatim)
// ---------------------------------------------------------------------------
__global__ __launch_bounds__(256) void refine_kernel(const float* __restrict__ qp,
                                                     const float* __restrict__ kp,
                                                     const int* __restrict__ idx,
                                                     const int* __restrict__ candIdx,
                                                     float* __restrict__ refPart) {
    const int blk = blockIdx.x;  // 256
    const int i = blk >> 3, c = blk & 7;
    const int b = i >> 3, h = i & 7;
    const int t = threadIdx.x;
    __shared__ float qc[64][40];
    __shared__ float Ks[128][40];

    {
        const int cand = t >> 2, dp = (t & 3) * 8;
        const int l = candIdx[i * 64 + cand];
        const float* src = qp + ((size_t)i * 2048 + l) * 32 + dp;
        *(float4*)&qc[cand][dp] = *(const float4*)(src);
        *(float4*)&qc[cand][dp + 4] = *(const float4*)(src + 4);
    }
    __syncthreads();

    const int cand = t >> 2, usub = t & 3;
    float qv[32];
#pragma unroll
    for (int z = 0; z < 8; ++z) {
        float4 a = *(const float4*)&qc[cand][z * 4];
        qv[4 * z] = a.x; qv[4 * z + 1] = a.y; qv[4 * z + 2] = a.z; qv[4 * z + 3] = a.w;
    }

    float m = -INFINITY;
    for (int s = 0; s < 2; ++s) {
        {
            const int r = t >> 1, half = t & 1;
            const int u = c * 256 + s * 128 + r;
            const float* krow = kp + (size_t)b * LD_ + (size_t)idx[u] * D_ + h * DH_ + half * 16;
#pragma unroll
            for (int z = 0; z < 4; ++z)
                *(float4*)&Ks[r][half * 16 + z * 4] = *(const float4*)(krow + z * 4);
        }
        __syncthreads();
        for (int ur = usub; ur < 128; ur += 4) {
            float a0 = 0, a1 = 0, a2 = 0, a3 = 0;
#pragma unroll
            for (int z = 0; z < 8; ++z) {
                float4 kv = *(const float4*)&Ks[ur][z * 4];
                a0 = fmaf(qv[4 * z], kv.x, a0);
                a1 = fmaf(qv[4 * z + 1], kv.y, a1);
                a2 = fmaf(qv[4 * z + 2], kv.z, a2);
                a3 = fmaf(qv[4 * z + 3], kv.w, a3);
            }
            m = fmaxf(m, (a0 + a1) + (a2 + a3));
        }
        __syncthreads();
    }
    m = fmaxf(m, __shfl_xor(m, 1, 64));
    m = fmaxf(m, __shfl_xor(m, 2, 64));
    if ((t & 3) == 0) refPart[((size_t)i * 8 + c) * 64 + cand] = m;
}

// ---------------------------------------------------------------------------
// Flash-style attention with select40 fused at the head (R4-R10 proven).
// Grid: 512 = i*16 + c, 320 threads.
// ---------------------------------------------------------------------------
#define SCP2 136  // sc row pad
#define VSP 36    // Vs row pad

__global__ __launch_bounds__(320) void attn_part(const float* __restrict__ qp,
                                                 const float* __restrict__ kp,
                                                 const float* __restrict__ vp,
                                                 const int* __restrict__ candIdx,
                                                 const float* __restrict__ refPart,
                                                 const float* __restrict__ Qmean,
                                                 float* __restrict__ mPart,
                                                 float* __restrict__ sPart,
                                                 float* __restrict__ oPart) {
    const int blk = blockIdx.x;  // 512 = i*16 + c
    const int i = blk >> 4, c = blk & 15;
    const int b = i >> 3, h = i & 7;
    const int t = threadIdx.x;

    __shared__ float Qs[40][32];
    __shared__ float Vs[128][VSP];
    __shared__ float sc[40][SCP2];
    __shared__ float mred[40], sred[40];
    __shared__ int topl[40];

    if (t < 64) {
        // verbatim select40 (one wave)
        const int l = candIdx[i * 64 + t];
        float m = -INFINITY;
#pragma unroll
        for (int cc = 0; cc < 8; ++cc) m = fmaxf(m, refPart[((size_t)i * 8 + cc) * 64 + t]);
        float Mex = m - Qmean[(size_t)i * 2048 + l];
        unsigned u32 = __float_as_uint(Mex);
        u32 = (u32 & 0x80000000u) ? ~u32 : (u32 | 0x80000000u);
        unsigned long long key = ((unsigned long long)u32 << 32) | (unsigned)l;
        for (int it = 0; it < 40; ++it) {
            unsigned long long k2 = key;
#pragma unroll
            for (int off = 1; off < 64; off <<= 1) k2 = ullmin_(k2, __shfl_xor(k2, off, 64));
            if (key == k2) {
                topl[it] = l;
                key = ~0ULL;
            }
        }
    } else {
        for (int e = t - 64; e < 1024; e += 256) {
            const int r = e >> 3, qq = e & 7;
            *(float4*)&Vs[r][qq * 4] =
                *(const float4*)(vp + (size_t)b * LD_ + (size_t)(c * 128 + r) * 256 + h * 32 + qq * 4);
        }
    }
    __syncthreads();

    {
        const int r = t >> 3, qq = t & 7;
        const int lq = topl[r];
        *(float4*)&Qs[r][qq * 4] = *(const float4*)(qp + ((size_t)i * 2048 + lq) * 32 + qq * 4);
    }
    __syncthreads();

    const float scale = 0.17677669529663687f;  // 1/sqrt(32)

    if (t < 256) {
        const int r = t >> 1;
        const int j0 = (t & 1) * 20;
        const float* kr = kp + (size_t)b * LD_ + (size_t)(c * 128 + r) * 256 + h * 32;
        float kv[32];
#pragma unroll
        for (int z = 0; z < 8; ++z) {
            float4 x = *(const float4*)(kr + z * 4);
            kv[4 * z] = x.x; kv[4 * z + 1] = x.y; kv[4 * z + 2] = x.z; kv[4 * z + 3] = x.w;
        }
#pragma unroll 4
        for (int jj = 0; jj < 20; ++jj) {
            const int j = j0 + jj;
            float a0 = 0, a1 = 0, a2 = 0, a3 = 0;
#pragma unroll
            for (int z = 0; z < 8; ++z) {
                const float4 q4 = *(const float4*)&Qs[j][z * 4];
                a0 = fmaf(kv[4 * z], q4.x, a0);
                a1 = fmaf(kv[4 * z + 1], q4.y, a1);
                a2 = fmaf(kv[4 * z + 2], q4.z, a2);
                a3 = fmaf(kv[4 * z + 3], q4.w, a3);
            }
            sc[j][r] = ((a0 + a1) + (a2 + a3)) * scale;
        }
    }
    __syncthreads();

    {
        const int w = t >> 6, lane = t & 63;
#pragma unroll
        for (int rr = 0; rr < 8; ++rr) {
            const int j = w * 8 + rr;
            float x0 = sc[j][lane], x1 = sc[j][lane + 64];
            float m = fmaxf(x0, x1);
#pragma unroll
            for (int off = 1; off < 64; off <<= 1) m = fmaxf(m, __shfl_xor(m, off, 64));
            const float e0 = __expf(x0 - m), e1 = __expf(x1 - m);
            sc[j][lane] = e0; sc[j][lane + 64] = e1;
            float s = e0 + e1;
#pragma unroll
            for (int off = 1; off < 64; off <<= 1) s += __shfl_xor(s, off, 64);
            if (lane == 0) { mred[j] = m; sred[j] = s; }
        }
    }
    __syncthreads();

    {
        const int j = t >> 3, qq = t & 7;
        float4 acc = make_float4(0.f, 0.f, 0.f, 0.f);
        for (int l = 0; l < 128; ++l) {
            const float p = sc[j][l];
            const float4 v4 = *(const float4*)&Vs[l][qq * 4];
            acc.x = fmaf(p, v4.x, acc.x);
            acc.y = fmaf(p, v4.y, acc.y);
            acc.z = fmaf(p, v4.z, acc.z);
            acc.w = fmaf(p, v4.w, acc.w);
        }
        const size_t o = (size_t)(i * NCH_ + c) * 40 + j;
        *(float4*)&oPart[o * 32 + qq * 4] = acc;
        if (qq == 0) { mPart[o] = mred[j]; sPart[o] = sred[j]; }
    }
}

// ---------------------------------------------------------------------------
// Parallel softmax-rescale combine v2 (R6 proven): grid 160, 256 thr.
// ---------------------------------------------------------------------------
__global__ __launch_bounds__(256) void attn_combine(const float* __restrict__ mPart,
                                                    const float* __restrict__ sPart,
                                                    const float* __restrict__ oPart,
                                                    float* __restrict__ attnOut) {
    const int blk = blockIdx.x;     // 160 = b*40 + j
    const int b = blk / 40, j = blk - b * 40;
    const int t = threadIdx.x;
    const int h = t >> 5, d = t & 31;
    const int i = b * 8 + h;

    float mv[NCH_];
    float M = -INFINITY;
#pragma unroll
    for (int c = 0; c < NCH_; ++c) {
        mv[c] = mPart[(size_t)(i * NCH_ + c) * 40 + j];
        M = fmaxf(M, mv[c]);
    }
    float S = 0.f, O = 0.f;
#pragma unroll
    for (int c = 0; c < NCH_; ++c) {
        const float sc_ = __expf(mv[c] - M);
        const size_t o = (size_t)(i * NCH_ + c) * 40 + j;
        S = fmaf(sPart[o], sc_, S);
        O = fmaf(oPart[o * 32 + d], sc_, O);
    }
    attnOut[((size_t)b * 40 + j) * 256 + h * 32 + d] = O / S;
}

// ---------------------------------------------------------------------------
// Final-projection GEMM (R1-proven): M=160, N=256, K=256 fp32 VALU.
// Grid (10,4) x 256 threads. X tile in LDS (broadcast, conflict-free).
// ---------------------------------------------------------------------------
__global__ __launch_bounds__(256) void gemm_out(const float* __restrict__ X,
                                                const float* __restrict__ Wc,
                                                const float* __restrict__ bias,
                                                float* __restrict__ Y) {
    const int t = threadIdx.x;
    const int rowBase = blockIdx.x * 16;   // 160 = 10*16 exact
    const int colBase = blockIdx.y * 64;
    const int col = colBase + (t & 63);
    const int rq = (t >> 6) * 4;           // rows rq..rq+3 of the tile

    __shared__ float Xs[16][256];
#pragma unroll
    for (int e = t; e < 1024; e += 256) {
        const int r = e >> 6, kq = (e & 63) * 4;
        *(float4*)&Xs[r][kq] = *(const float4*)(X + (size_t)(rowBase + r) * 256 + kq);
    }
    __syncthreads();

    const float* wr = Wc + (size_t)col * 256;
    float acc[4] = {0.f, 0.f, 0.f, 0.f};
#pragma unroll 8
    for (int k = 0; k < 256; k += 4) {
        const float4 wv = *(const float4*)(wr + k);
#pragma unroll
        for (int r = 0; r < 4; ++r) {
            acc[r] = fmaf(Xs[rq + r][k + 0], wv.x, acc[r]);
            acc[r] = fmaf(Xs[rq + r][k + 1], wv.y, acc[r]);
            acc[r] = fmaf(Xs[rq + r][k + 2], wv.z, acc[r]);
            acc[r] = fmaf(Xs[rq + r][k + 3], wv.w, acc[r]);
        }
    }

    const float bv = bias[col];
#pragma unroll
    for (int r = 0; r < 4; ++r)
        Y[(size_t)(rowBase + rq + r) * 256 + col] = acc[r] + bv;
}

// ---------------------------------------------------------------------------
extern "C" void kernel_launch(void* const* d_in, const int* in_sizes, int n_in,
                              void* d_out, int out_size, void* d_ws, size_t ws_size,
                              hipStream_t stream) {
    const float* q  = (const float*)d_in[0];
    const float* k  = (const float*)d_in[1];
    const float* v  = (const float*)d_in[2];
    const float* Wq = (const float*)d_in[3];
    const float* bq = (const float*)d_in[4];
    const float* Wk = (const float*)d_in[5];
    const float* bk = (const float*)d_in[6];
    const float* Wv = (const float*)d_in[7];
    const float* bv = (const float*)d_in[8];
    const float* Wc = (const float*)d_in[9];
    const float* bc = (const float*)d_in[10];
    const int* idx  = (const int*)d_in[11];
    float* out = (float*)d_out;

    // Workspace map (peak ~57.5 MB):
    //  [0,8)MB qp | [8,16) kp | [16,24) vp
    //  [24,56) X-planes (Xh 24-36, Xm 36-48, Xl 48-56) -- live only until
    //          gemm_proj completes, then the region is reused:
    //  [24,28) Khi | [28,32) Klo (kconv, after gemm_proj)
    //  [24,*)  mPart/sPart/oPart (attn partials, after mpart)
    //  32M+0 Mv(256K) | +256K Qmean(256K) | +512K Ksum32(128K)
    //  +640K candIdx(8K) | +656K refPart(64K) | +720K attnOut(160K)
    //  56M Whs(384K) | 56M+512K Wms(384K) | 57M Wls(384K)
    char* w = (char*)d_ws;
    float*          qp      = (float*)(w);
    float*          kp      = (float*)(w + (8u << 20));
    float*          vp      = (float*)(w + (16u << 20));
    unsigned short* Xh      = (unsigned short*)(w + (24u << 20));
    unsigned short* Xm      = (unsigned short*)(w + (36u << 20));
    unsigned short* Xl      = (unsigned short*)(w + (48u << 20));
    unsigned short* Khi     = (unsigned short*)(w + (24u << 20));
    unsigned short* Klo     = (unsigned short*)(w + (28u << 20));
    float*          Mv      = (float*)(w + (32u << 20));
    float*          Qmean   = (float*)(w + (32u << 20) + (256u << 10));
    float*          Ksum32  = (float*)(w + (32u << 20) + (512u << 10));
    int*            candIdx = (int*)  (w + (32u << 20) + (640u << 10));
    float*          refPart = (float*)(w + (32u << 20) + (656u << 10));
    float*          attnOut = (float*)(w + (32u << 20) + (720u << 10));
    unsigned short* Whs     = (unsigned short*)(w + (56u << 20));
    unsigned short* Wms     = (unsigned short*)(w + (56u << 20) + (512u << 10));
    unsigned short* Wls     = (unsigned short*)(w + (57u << 20));
    float*          mPart   = (float*)(w + (24u << 20));                // after mpart_mfma
    float*          sPart   = (float*)(w + (24u << 20) + (128u << 10));
    float*          oPart   = (float*)(w + (24u << 20) + (256u << 10)); // 2.62 MB

    // 10 launches.
    hipLaunchKernelGGL(wsplit, dim3(192), dim3(256), 0, stream, Wq, Wk, Wv, Whs, Wms, Wls);
    hipLaunchKernelGGL(xsplit, dim3(6144), dim3(256), 0, stream, q, k, v, Xh, Xm, Xl);
    hipLaunchKernelGGL(gemm_proj, dim3(128, 2, 3), dim3(256), 0, stream,
                       Xh, Xm, Xl, Whs, Wms, Wls, bq, bk, bv, qp, kp, vp);
    hipLaunchKernelGGL(kconv_ksum, dim3(1024), dim3(256), 0, stream, kp, idx, Khi, Klo, Ksum32);
    hipLaunchKernelGGL(mpart_mfma, dim3(512), dim3(256), 0, stream, qp, Khi, Klo, Ksum32, Mv, Qmean);
    hipLaunchKernelGGL(topk64_fast, dim3(32), dim3(256), 0, stream, Mv, candIdx);
    hipLaunchKernelGGL(refine_kernel, dim3(256), dim3(256), 0, stream, qp, kp, idx, candIdx, refPart);
    hipLaunchKernelGGL(attn_part, dim3(512), dim3(320), 0, stream,
                       qp, kp, vp, candIdx, refPart, Qmean, mPart, sPart, oPart);
    hipLaunchKernelGGL(attn_combine, dim3(160), dim3(256), 0, stream, mPart, sPart, oPart, attnOut);
    hipLaunchKernelGGL(gemm_out, dim3(10, 4), dim3(256), 0, stream, attnOut, Wc, bc, out);
}

// Round 12
// 209.722 us; speedup vs baseline: 1.1430x; 1.1430x over previous
//
#include <hip/hip_runtime.h>
#include <math.h>

// Problem constants
#define B_ 4
#define L_ 2048
#define D_ 256
#define H_ 8
#define DH_ 32
#define NH_ 32           // B*H
#define U_ 40
#define LD_ 524288       // L_*D_ floats per batch
#define NCH_ 16          // attention L-chunks

typedef __attribute__((ext_vector_type(8))) short short8;
typedef __attribute__((ext_vector_type(4))) float floatx4;

static __device__ __forceinline__ unsigned long long ullmin_(unsigned long long a, unsigned long long b) {
    return a < b ? a : b;
}
static __device__ __forceinline__ unsigned short f2bf_rne(float x) {
    unsigned u = __float_as_uint(x);
    unsigned r = u + 0x7FFFu + ((u >> 16) & 1u);
    return (unsigned short)(r >> 16);
}
static __device__ __forceinline__ float bf2f(unsigned short h) {
    return __uint_as_float(((unsigned)h) << 16);
}

// ---------------------------------------------------------------------------
// W pre-split v2 (R9 proven): fp32 W[col][k] -> THREE bf16 planes in
// LANE-MAJOR fragment tiles (staging + ds_read conflict-free).
// R11 lesson: pre-splitting A (xsplit) REGRESSED -- 112MB HBM round-trip to
// save ~15us VALU. B pre-split wins only because B is reused 128x.
// ---------------------------------------------------------------------------
__global__ __launch_bounds__(256) void wsplit(const float* __restrict__ Wq,
                                              const float* __restrict__ Wk,
                                              const float* __restrict__ Wv,
                                              unsigned short* __restrict__ Whs,
                                              unsigned short* __restrict__ Wms,
                                              unsigned short* __restrict__ Wls) {
    const int g = blockIdx.x * 256 + threadIdx.x;   // 0..49151
    const int mat = g >> 14;                         // 3 mats * 16384 float4
    const int rem = g & 16383;
    const int col = rem >> 6;                        // 0..255
    const int k4 = rem & 63;                         // 0..63 (k = k4*4)
    const float* W = (mat == 0) ? Wq : (mat == 1) ? Wk : Wv;
    const float4 x = *(const float4*)(W + (size_t)col * 256 + k4 * 4);
    float xs[4] = {x.x, x.y, x.z, x.w};
    unsigned short hv[4], mv[4], lv[4];
#pragma unroll
    for (int j = 0; j < 4; ++j) {
        hv[j] = f2bf_rne(xs[j]);
        const float e1 = xs[j] - bf2f(hv[j]);
        mv[j] = f2bf_rne(e1);
        const float e2 = e1 - bf2f(mv[j]);
        lv[j] = f2bf_rne(e2);
    }
    const int colblk = col >> 6, c64 = col & 63;
    const int jt = c64 >> 4, cin = c64 & 15;
    const int kt = k4 >> 3, g8 = k4 & 7;
    const int quad = g8 >> 1, half = g8 & 1;
    const size_t o = ((((size_t)mat * 4 + colblk) * 8 + kt) << 11) +
                     jt * 512 + (quad * 16 + cin) * 8 + half * 4;
    *(ushort4*)(Whs + o) = make_ushort4(hv[0], hv[1], hv[2], hv[3]);
    *(ushort4*)(Wms + o) = make_ushort4(mv[0], mv[1], mv[2], mv[3]);
    *(ushort4*)(Wls + o) = make_ushort4(lv[0], lv[1], lv[2], lv[3]);
}

// ---------------------------------------------------------------------------
// Batched projection GEMM v7: v5 (R9 proven, LDS-staged B double-buffered)
// + A-chain software pipeline: A float4 loads issued ONE ITERATION EARLY
// (with the B staging loads), conversion moved to the iteration TAIL
// (overlaps ds_write/vmcnt drain). MFMA section starts with A ready in regs
// -- removes ~500cyc of load+convert from the per-iter critical path.
// Conversion values / MFMA order verbatim -> qp,kp,vp bit-identical.
// Grid (128,2,3), block = 64 rows x 128 cols, 4 waves, 48KB LDS.
// ---------------------------------------------------------------------------
__global__ __launch_bounds__(256) void gemm_proj(const float* __restrict__ q,
                                                 const float* __restrict__ k,
                                                 const float* __restrict__ v,
                                                 const unsigned short* __restrict__ Whs,
                                                 const unsigned short* __restrict__ Wms,
                                                 const unsigned short* __restrict__ Wls,
                                                 const float* __restrict__ bq,
                                                 const float* __restrict__ bk,
                                                 const float* __restrict__ bv,
                                                 float* __restrict__ qp,
                                                 float* __restrict__ kp,
                                                 float* __restrict__ vp) {
    const int mat = blockIdx.z;
    const float* X = (mat == 0) ? q : (mat == 1) ? k : v;
    const float* bias = (mat == 0) ? bq : (mat == 1) ? bk : bv;
    float* Y = (mat == 0) ? qp : (mat == 1) ? kp : vp;
    const bool vmat = (mat == 2);

    const int t = threadIdx.x;
    const int w = t >> 6, lane = t & 63;
    const int lq = lane & 15, quad = lane >> 4;
    const int rowBase = blockIdx.x * 64 + w * 16;   // wave owns 16 rows
    const int colBase = blockIdx.y * 128;           // block owns 128 cols
    const int nseg = vmat ? 16 : 24;                // V skips the l-plane

    __shared__ unsigned short Bls[2][12288];        // 48 KB

    floatx4 acc[8];
#pragma unroll
    for (int nt2 = 0; nt2 < 8; ++nt2) acc[nt2] = (floatx4){0.f, 0.f, 0.f, 0.f};

    auto gsrc = [&](int s, int kt) -> const unsigned short* {
        const int p = s >> 3, rm = s & 7, chunk = rm >> 2, jj = rm & 3;
        const unsigned short* Wp = (p == 0) ? Whs : (p == 1) ? Wms : Wls;
        return Wp + (((((size_t)mat * 4 + ((blockIdx.y << 1) | chunk)) * 8 + kt) << 11) +
                     jj * 512 + lane * 8);
    };
    const float* xrow = X + (size_t)(rowBase + lq) * 256 + quad * 8;

    // helper: convert 8 fp32 -> 3-way (2-way for V) bf16 split, verbatim RNE
    auto convertA = [&](const float4& x0, const float4& x1,
                        short8& Ah, short8& Am, short8& Al) {
        float xs[8] = {x0.x, x0.y, x0.z, x0.w, x1.x, x1.y, x1.z, x1.w};
#pragma unroll
        for (int j = 0; j < 8; ++j) {
            const unsigned short h = f2bf_rne(xs[j]);
            const float e1 = xs[j] - bf2f(h);
            const unsigned short md = f2bf_rne(e1);
            Ah[j] = (short)h;
            Am[j] = (short)md;
            if (!vmat) {
                const float e2 = e1 - bf2f(md);
                Al[j] = (short)f2bf_rne(e2);
            }
        }
    };

    // prologue: stage B(kt=0) into buf 0; load+convert A(0)
#pragma unroll
    for (int n = 0; n < 6; ++n) {
        const int s = w + n * 4;
        if (s < nseg)
            *(short8*)&Bls[0][s * 512 + lane * 8] = *(const short8*)gsrc(s, 0);
    }
    short8 Ah, Am, Al;
    {
        const float4 x0 = *(const float4*)(xrow);
        const float4 x1 = *(const float4*)(xrow + 4);
        convertA(x0, x1, Ah, Am, Al);
    }
    __syncthreads();

    for (int kt = 0; kt < 8; ++kt) {
        const int buf = kt & 1;

        // T14 async-split: issue next tile's global loads EARLY (B stg + A floats)
        short8 stg[6];
        float4 nx0, nx1;
        if (kt < 7) {
#pragma unroll
            for (int n = 0; n < 6; ++n) {
                const int s = w + n * 4;
                if (s < nseg) stg[n] = *(const short8*)gsrc(s, kt + 1);
            }
            nx0 = *(const float4*)(xrow + (kt + 1) * 32);
            nx1 = *(const float4*)(xrow + (kt + 1) * 32 + 4);
        }

        // 8 nt-tiles from LDS: conflict-free ds_read_b128, 6 (or 3) MFMAs;
        // A is ALREADY in registers (converted last iteration).
        const unsigned short* Bb = Bls[buf];
#pragma unroll
        for (int nt2 = 0; nt2 < 8; ++nt2) {
            const int boff = ((nt2 >> 2) << 11) + ((nt2 & 3) << 9) + lane * 8;
            const short8 Bh = *(const short8*)&Bb[boff];
            const short8 Bm = *(const short8*)&Bb[4096 + boff];
            floatx4 a = acc[nt2];
            if (!vmat) {
                const short8 Bl = *(const short8*)&Bb[8192 + boff];
                a = __builtin_amdgcn_mfma_f32_16x16x32_bf16(Am, Bm, a, 0, 0, 0);
                a = __builtin_amdgcn_mfma_f32_16x16x32_bf16(Ah, Bl, a, 0, 0, 0);
                a = __builtin_amdgcn_mfma_f32_16x16x32_bf16(Al, Bh, a, 0, 0, 0);
                a = __builtin_amdgcn_mfma_f32_16x16x32_bf16(Ah, Bm, a, 0, 0, 0);
                a = __builtin_amdgcn_mfma_f32_16x16x32_bf16(Am, Bh, a, 0, 0, 0);
                a = __builtin_amdgcn_mfma_f32_16x16x32_bf16(Ah, Bh, a, 0, 0, 0);
            } else {
                a = __builtin_amdgcn_mfma_f32_16x16x32_bf16(Ah, Bm, a, 0, 0, 0);
                a = __builtin_amdgcn_mfma_f32_16x16x32_bf16(Am, Bh, a, 0, 0, 0);
                a = __builtin_amdgcn_mfma_f32_16x16x32_bf16(Ah, Bh, a, 0, 0, 0);
            }
            acc[nt2] = a;
        }

        // tail: convert next A (overlaps MFMA drain / vmcnt wait), write B stg
        if (kt < 7) {
            convertA(nx0, nx1, Ah, Am, Al);
#pragma unroll
            for (int n = 0; n < 6; ++n) {
                const int s = w + n * 4;
                if (s < nseg)
                    *(short8*)&Bls[buf ^ 1][s * 512 + lane * 8] = stg[n];
            }
        }
        __syncthreads();
    }

#pragma unroll
    for (int nt2 = 0; nt2 < 8; ++nt2) {
        const int c = colBase + nt2 * 16 + lq;
        const float bv_ = bias[c];
#pragma unroll
        for (int r = 0; r < 4; ++r) {
            const int mr = rowBase + quad * 4 + r;
            Y[(size_t)mr * 256 + c] = acc[nt2][r] + bv_;
        }
    }
}

// ---------------------------------------------------------------------------
// kconv + ksum partials (R9 proven), 1024 blocks (i*32 + uc), 64 u each.
// ---------------------------------------------------------------------------
__global__ __launch_bounds__(256) void kconv_ksum(const float* __restrict__ kp,
                                                  const int* __restrict__ idx,
                                                  unsigned short* __restrict__ Khi,
                                                  unsigned short* __restrict__ Klo,
                                                  float* __restrict__ Ksum32) {
    const int blk = blockIdx.x;  // 1024: i*32 + uc
    const int i = blk >> 5, uc = blk & 31;
    const int b = i >> 3, h = i & 7;
    const int t = threadIdx.x;
    const int dq = (t & 7) * 4;
    const int ur = t >> 3;  // 0..31

    __shared__ float part[32][36];
    float ksum[4] = {0.f, 0.f, 0.f, 0.f};

#pragma unroll
    for (int p = 0; p < 2; ++p) {
        int u = uc * 64 + p * 32 + ur;
        const float4 x = *(const float4*)(kp + (size_t)b * LD_ + (size_t)idx[u] * D_ + h * DH_ + dq);
        float xs[4] = {x.x, x.y, x.z, x.w};
        unsigned short hv[4], lv[4];
#pragma unroll
        for (int j = 0; j < 4; ++j) {
            ksum[j] += xs[j];
            hv[j] = f2bf_rne(xs[j]);
            lv[j] = f2bf_rne(xs[j] - bf2f(hv[j]));
        }
        size_t o = ((size_t)i * 2048 + u) * 32 + dq;
        *(ushort4*)(Khi + o) = make_ushort4(hv[0], hv[1], hv[2], hv[3]);
        *(ushort4*)(Klo + o) = make_ushort4(lv[0], lv[1], lv[2], lv[3]);
    }
#pragma unroll
    for (int j = 0; j < 4; ++j) part[ur][dq + j] = ksum[j];
    __syncthreads();
    if (t < 32) {
        float s = 0.f;
#pragma unroll 8
        for (int u2 = 0; u2 < 32; ++u2) s += part[u2][t];
        Ksum32[(size_t)blk * 32 + t] = s;
    }
}

// ---------------------------------------------------------------------------
// Approx M-sweep on MFMA (R9 proven, lt=4, grid 1024) + fused Ssum reduce.
// ---------------------------------------------------------------------------
__global__ __launch_bounds__(256) void mpart_mfma(const float* __restrict__ qp,
                                                  const unsigned short* __restrict__ Khi,
                                                  const unsigned short* __restrict__ Klo,
                                                  const float* __restrict__ Ksum32,
                                                  float* __restrict__ Mv,
                                                  float* __restrict__ Qmean) {
    const int blk = blockIdx.x;
    const int i = blk >> 5;
    const int lg = blk & 31;
    const int t = threadIdx.x;
    const int w = t >> 6;
    const int lane = t & 63;
    const int lq = lane & 15;
    const int quad = lane >> 4;

    __shared__ float ssum[32];
    __shared__ float red[4][64];
    if (t < 32) {
        float s = 0.f;
#pragma unroll 8
        for (int uc = 0; uc < 32; ++uc) s += Ksum32[((size_t)i * 32 + uc) * 32 + t];
        ssum[t] = s;
    }

    short8 Ah[4], Al[4];
#pragma unroll
    for (int lt = 0; lt < 4; ++lt) {
        const int l = lg * 64 + lt * 16 + lq;
        const float* qrow = qp + ((size_t)i * 2048 + l) * 32 + quad * 8;
        float4 x0 = *(const float4*)(qrow);
        float4 x1 = *(const float4*)(qrow + 4);
        float xs[8] = {x0.x, x0.y, x0.z, x0.w, x1.x, x1.y, x1.z, x1.w};
#pragma unroll
        for (int j = 0; j < 8; ++j) {
            unsigned short h = f2bf_rne(xs[j]);
            unsigned short lo = f2bf_rne(xs[j] - bf2f(h));
            Ah[lt][j] = (short)h;
            Al[lt][j] = (short)lo;
        }
    }

    floatx4 rmax[4];
#pragma unroll
    for (int lt = 0; lt < 4; ++lt)
        rmax[lt] = (floatx4){-INFINITY, -INFINITY, -INFINITY, -INFINITY};

    const size_t kfrag = ((size_t)i * 2048 + w * 512 + lq) * 32 + quad * 8;
    const unsigned short* ph = Khi + kfrag;
    const unsigned short* pl = Klo + kfrag;
#pragma unroll 2
    for (int s = 0; s < 32; ++s) {
        short8 Bh = *(const short8*)(ph + (size_t)s * 512);
        short8 Bl = *(const short8*)(pl + (size_t)s * 512);
#pragma unroll
        for (int lt = 0; lt < 4; ++lt) {
            floatx4 acc = (floatx4){0.f, 0.f, 0.f, 0.f};
            acc = __builtin_amdgcn_mfma_f32_16x16x32_bf16(Al[lt], Bh, acc, 0, 0, 0);
            acc = __builtin_amdgcn_mfma_f32_16x16x32_bf16(Ah[lt], Bl, acc, 0, 0, 0);
            acc = __builtin_amdgcn_mfma_f32_16x16x32_bf16(Ah[lt], Bh, acc, 0, 0, 0);
#pragma unroll
            for (int r = 0; r < 4; ++r) rmax[lt][r] = fmaxf(rmax[lt][r], acc[r]);
        }
    }

#pragma unroll
    for (int lt = 0; lt < 4; ++lt)
#pragma unroll
        for (int r = 0; r < 4; ++r) {
            float v = rmax[lt][r];
#pragma unroll
            for (int off = 1; off < 16; off <<= 1)
                v = fmaxf(v, __shfl_xor(v, off, 64));
            rmax[lt][r] = v;
        }
    if (lq == 0) {
#pragma unroll
        for (int lt = 0; lt < 4; ++lt)
#pragma unroll
            for (int r = 0; r < 4; ++r)
                red[w][lt * 16 + quad * 4 + r] = rmax[lt][r];
    }
    __syncthreads();
    if (t < 64) {
        const int l = lg * 64 + t;
        float m = fmaxf(fmaxf(red[0][t], red[1][t]), fmaxf(red[2][t], red[3][t]));
        const float4* q4 = (const float4*)(qp + ((size_t)i * 2048 + l) * 32);
        const float4* s4 = (const float4*)ssum;
        float qs = 0.f;
#pragma unroll
        for (int z = 0; z < 8; ++z) {
            float4 a = q4[z];
            float4 c = s4[z];
            qs = fmaf(a.x, c.x, qs);
            qs = fmaf(a.y, c.y, qs);
            qs = fmaf(a.z, c.z, qs);
            qs = fmaf(a.w, c.w, qs);
        }
        const float qm = qs * (1.0f / 2048.0f);
        Qmean[(size_t)i * 2048 + l] = qm;
        Mv[(size_t)i * 2048 + l] = m - qm;
    }
}

// ---------------------------------------------------------------------------
// FAST bottom-64: 4-level byte radix-select (R5 proven). Grid 32 x 256.
// ---------------------------------------------------------------------------
__global__ __launch_bounds__(256) void topk64_fast(const float* __restrict__ Mv,
                                                   int* __restrict__ candIdx) {
    const int i = blockIdx.x;
    const int t = threadIdx.x;
    const int w = t >> 6, lane = t & 63;

    __shared__ unsigned hist[256];
    __shared__ unsigned sh_prefix, sh_selBelow;
    __shared__ unsigned cnt;
    __shared__ int candLds[64];
    __shared__ unsigned long long wred[4];

    unsigned v[8];
#pragma unroll
    for (int j = 0; j < 8; ++j) {
        const unsigned u = __float_as_uint(Mv[(size_t)i * 2048 + t + 256 * j]);
        v[j] = (u & 0x80000000u) ? ~u : (u | 0x80000000u);  // monotone map
    }

    if (t == 0) { sh_prefix = 0u; sh_selBelow = 0u; cnt = 0u; }

    for (int level = 0; level < 4; ++level) {
        const int shift = 24 - 8 * level;
        __syncthreads();                       // publish sh_* ; prev scan done
        const unsigned prefHi = sh_prefix;
        const unsigned selB = sh_selBelow;
        const unsigned mask = (level == 0) ? 0u : (0xFFFFFFFFu << (shift + 8));
        hist[t] = 0u;
        __syncthreads();
#pragma unroll
        for (int j = 0; j < 8; ++j)
            if ((v[j] & mask) == prefHi)
                atomicAdd(&hist[(v[j] >> shift) & 255u], 1u);
        __syncthreads();
        if (t < 64) {
            const unsigned c0 = hist[t * 4 + 0], c1 = hist[t * 4 + 1];
            const unsigned c2 = hist[t * 4 + 2], c3 = hist[t * 4 + 3];
            const unsigned i0 = c0, i1 = c0 + c1, i2 = i1 + c2, i3 = i2 + c3;
            unsigned x = i3;
#pragma unroll
            for (int off = 1; off < 64; off <<= 1) {
                const unsigned y = __shfl_up(x, off, 64);
                if (t >= off) x += y;
            }
            const unsigned excl = x - i3;          // wave-exclusive sum
            const unsigned r = 64u - selB;         // still needed, >= 1
            const unsigned long long ball = __ballot(x >= r);
            const int flane = __ffsll(ball) - 1;   // invariant: exists
            if (t == flane) {
                unsigned k, ce;
                if (excl + i0 >= r)      { k = 0u; ce = excl; }
                else if (excl + i1 >= r) { k = 1u; ce = excl + i0; }
                else if (excl + i2 >= r) { k = 2u; ce = excl + i1; }
                else                     { k = 3u; ce = excl + i2; }
                sh_prefix = prefHi | (((unsigned)t * 4u + k) << shift);
                sh_selBelow = selB + ce;
            }
        }
    }
    __syncthreads();
    const unsigned thr = sh_prefix;            // exact 64th-smallest value
    const unsigned selB = sh_selBelow;         // #keys strictly below thr (<64)
    const int rem = 64 - (int)selB;            // >= 1, filled from ties at thr

    unsigned long long keys[8];
#pragma unroll
    for (int j = 0; j < 8; ++j) {
        const int l = t + 256 * j;
        if (v[j] < thr) {
            const unsigned p = atomicAdd(&cnt, 1u);
            candLds[p] = l;
            keys[j] = ~0ULL;
        } else if (v[j] == thr) {
            keys[j] = ((unsigned long long)v[j] << 32) | (unsigned)l;
        } else {
            keys[j] = ~0ULL;
        }
    }
    __syncthreads();

    for (int it = 0; it < rem; ++it) {
        unsigned long long best = keys[0];
#pragma unroll
        for (int j = 1; j < 8; ++j) best = ullmin_(best, keys[j]);
#pragma unroll
        for (int off = 1; off < 64; off <<= 1)
            best = ullmin_(best, __shfl_xor(best, off, 64));
        if (lane == 0) wred[w] = best;
        __syncthreads();
        const unsigned long long m = ullmin_(ullmin_(wred[0], wred[1]), ullmin_(wred[2], wred[3]));
        if (t == 0) candLds[selB + it] = (int)(m & 0xffffffffu);
#pragma unroll
        for (int j = 0; j < 8; ++j)
            if (keys[j] == m) keys[j] = ~0ULL;
        __syncthreads();
    }

    if (t < 64) candIdx[i * 64 + t] = candLds[t];
}

// ---------------------------------------------------------------------------
// Exact fp32 refine: grid 256 = i*8 + chunk (256 u each). (verbatim)
// ---------------------------------------------------------------------------
__global__ __launch_bounds__(256) void refine_kernel(const float* __restrict__ qp,
                                                     const float* __restrict__ kp,
                                                     const int* __restrict__ idx,
                                                     const int* __restrict__ candIdx,
                                                     float* __restrict__ refPart) {
    const int blk = blockIdx.x;  // 256
    const int i = blk >> 3, c = blk & 7;
    const int b = i >> 3, h = i & 7;
    const int t = threadIdx.x;
    __shared__ float qc[64][40];
    __shared__ float Ks[128][40];

    {
        const int cand = t >> 2, dp = (t & 3) * 8;
        const int l = candIdx[i * 64 + cand];
        const float* src = qp + ((size_t)i * 2048 + l) * 32 + dp;
        *(float4*)&qc[cand][dp] = *(const float4*)(src);
        *(float4*)&qc[cand][dp + 4] = *(const float4*)(src + 4);
    }
    __syncthreads();

    const int cand = t >> 2, usub = t & 3;
    float qv[32];
#pragma unroll
    for (int z = 0; z < 8; ++z) {
        float4 a = *(const float4*)&qc[cand][z * 4];
        qv[4 * z] = a.x; qv[4 * z + 1] = a.y; qv[4 * z + 2] = a.z; qv[4 * z + 3] = a.w;
    }

    float m = -INFINITY;
    for (int s = 0; s < 2; ++s) {
        {
            const int r = t >> 1, half = t & 1;
            const int u = c * 256 + s * 128 + r;
            const float* krow = kp + (size_t)b * LD_ + (size_t)idx[u] * D_ + h * DH_ + half * 16;
#pragma unroll
            for (int z = 0; z < 4; ++z)
                *(float4*)&Ks[r][half * 16 + z * 4] = *(const float4*)(krow + z * 4);
        }
        __syncthreads();
        for (int ur = usub; ur < 128; ur += 4) {
            float a0 = 0, a1 = 0, a2 = 0, a3 = 0;
#pragma unroll
            for (int z = 0; z < 8; ++z) {
                float4 kv = *(const float4*)&Ks[ur][z * 4];
                a0 = fmaf(qv[4 * z], kv.x, a0);
                a1 = fmaf(qv[4 * z + 1], kv.y, a1);
                a2 = fmaf(qv[4 * z + 2], kv.z, a2);
                a3 = fmaf(qv[4 * z + 3], kv.w, a3);
            }
            m = fmaxf(m, (a0 + a1) + (a2 + a3));
        }
        __syncthreads();
    }
    m = fmaxf(m, __shfl_xor(m, 1, 64));
    m = fmaxf(m, __shfl_xor(m, 2, 64));
    if ((t & 3) == 0) refPart[((size_t)i * 8 + c) * 64 + cand] = m;
}

// ---------------------------------------------------------------------------
// Flash-style attention with select40 fused at the head (R4-R10 proven).
// Grid: 512 = i*16 + c, 320 threads.
// ---------------------------------------------------------------------------
#define SCP2 136  // sc row pad
#define VSP 36    // Vs row pad

__global__ __launch_bounds__(320) void attn_part(const float* __restrict__ qp,
                                                 const float* __restrict__ kp,
                                                 const float* __restrict__ vp,
                                                 const int* __restrict__ candIdx,
                                                 const float* __restrict__ refPart,
                                                 const float* __restrict__ Qmean,
                                                 float* __restrict__ mPart,
                                                 float* __restrict__ sPart,
                                                 float* __restrict__ oPart) {
    const int blk = blockIdx.x;  // 512 = i*16 + c
    const int i = blk >> 4, c = blk & 15;
    const int b = i >> 3, h = i & 7;
    const int t = threadIdx.x;

    __shared__ float Qs[40][32];
    __shared__ float Vs[128][VSP];
    __shared__ float sc[40][SCP2];
    __shared__ float mred[40], sred[40];
    __shared__ int topl[40];

    if (t < 64) {
        // verbatim select40 (one wave)
        const int l = candIdx[i * 64 + t];
        float m = -INFINITY;
#pragma unroll
        for (int cc = 0; cc < 8; ++cc) m = fmaxf(m, refPart[((size_t)i * 8 + cc) * 64 + t]);
        float Mex = m - Qmean[(size_t)i * 2048 + l];
        unsigned u32 = __float_as_uint(Mex);
        u32 = (u32 & 0x80000000u) ? ~u32 : (u32 | 0x80000000u);
        unsigned long long key = ((unsigned long long)u32 << 32) | (unsigned)l;
        for (int it = 0; it < 40; ++it) {
            unsigned long long k2 = key;
#pragma unroll
            for (int off = 1; off < 64; off <<= 1) k2 = ullmin_(k2, __shfl_xor(k2, off, 64));
            if (key == k2) {
                topl[it] = l;
                key = ~0ULL;
            }
        }
    } else {
        for (int e = t - 64; e < 1024; e += 256) {
            const int r = e >> 3, qq = e & 7;
            *(float4*)&Vs[r][qq * 4] =
                *(const float4*)(vp + (size_t)b * LD_ + (size_t)(c * 128 + r) * 256 + h * 32 + qq * 4);
        }
    }
    __syncthreads();

    {
        const int r = t >> 3, qq = t & 7;
        const int lq = topl[r];
        *(float4*)&Qs[r][qq * 4] = *(const float4*)(qp + ((size_t)i * 2048 + lq) * 32 + qq * 4);
    }
    __syncthreads();

    const float scale = 0.17677669529663687f;  // 1/sqrt(32)

    if (t < 256) {
        const int r = t >> 1;
        const int j0 = (t & 1) * 20;
        const float* kr = kp + (size_t)b * LD_ + (size_t)(c * 128 + r) * 256 + h * 32;
        float kv[32];
#pragma unroll
        for (int z = 0; z < 8; ++z) {
            float4 x = *(const float4*)(kr + z * 4);
            kv[4 * z] = x.x; kv[4 * z + 1] = x.y; kv[4 * z + 2] = x.z; kv[4 * z + 3] = x.w;
        }
#pragma unroll 4
        for (int jj = 0; jj < 20; ++jj) {
            const int j = j0 + jj;
            float a0 = 0, a1 = 0, a2 = 0, a3 = 0;
#pragma unroll
            for (int z = 0; z < 8; ++z) {
                const float4 q4 = *(const float4*)&Qs[j][z * 4];
                a0 = fmaf(kv[4 * z], q4.x, a0);
                a1 = fmaf(kv[4 * z + 1], q4.y, a1);
                a2 = fmaf(kv[4 * z + 2], q4.z, a2);
                a3 = fmaf(kv[4 * z + 3], q4.w, a3);
            }
            sc[j][r] = ((a0 + a1) + (a2 + a3)) * scale;
        }
    }
    __syncthreads();

    {
        const int w = t >> 6, lane = t & 63;
#pragma unroll
        for (int rr = 0; rr < 8; ++rr) {
            const int j = w * 8 + rr;
            float x0 = sc[j][lane], x1 = sc[j][lane + 64];
            float m = fmaxf(x0, x1);
#pragma unroll
            for (int off = 1; off < 64; off <<= 1) m = fmaxf(m, __shfl_xor(m, off, 64));
            const float e0 = __expf(x0 - m), e1 = __expf(x1 - m);
            sc[j][lane] = e0; sc[j][lane + 64] = e1;
            float s = e0 + e1;
#pragma unroll
            for (int off = 1; off < 64; off <<= 1) s += __shfl_xor(s, off, 64);
            if (lane == 0) { mred[j] = m; sred[j] = s; }
        }
    }
    __syncthreads();

    {
        const int j = t >> 3, qq = t & 7;
        float4 acc = make_float4(0.f, 0.f, 0.f, 0.f);
        for (int l = 0; l < 128; ++l) {
            const float p = sc[j][l];
            const float4 v4 = *(const float4*)&Vs[l][qq * 4];
            acc.x = fmaf(p, v4.x, acc.x);
            acc.y = fmaf(p, v4.y, acc.y);
            acc.z = fmaf(p, v4.z, acc.z);
            acc.w = fmaf(p, v4.w, acc.w);
        }
        const size_t o = (size_t)(i * NCH_ + c) * 40 + j;
        *(float4*)&oPart[o * 32 + qq * 4] = acc;
        if (qq == 0) { mPart[o] = mred[j]; sPart[o] = sred[j]; }
    }
}

// ---------------------------------------------------------------------------
// Parallel softmax-rescale combine v2 (R6 proven): grid 160, 256 thr.
// ---------------------------------------------------------------------------
__global__ __launch_bounds__(256) void attn_combine(const float* __restrict__ mPart,
                                                    const float* __restrict__ sPart,
                                                    const float* __restrict__ oPart,
                                                    float* __restrict__ attnOut) {
    const int blk = blockIdx.x;     // 160 = b*40 + j
    const int b = blk / 40, j = blk - b * 40;
    const int t = threadIdx.x;
    const int h = t >> 5, d = t & 31;
    const int i = b * 8 + h;

    float mv[NCH_];
    float M = -INFINITY;
#pragma unroll
    for (int c = 0; c < NCH_; ++c) {
        mv[c] = mPart[(size_t)(i * NCH_ + c) * 40 + j];
        M = fmaxf(M, mv[c]);
    }
    float S = 0.f, O = 0.f;
#pragma unroll
    for (int c = 0; c < NCH_; ++c) {
        const float sc_ = __expf(mv[c] - M);
        const size_t o = (size_t)(i * NCH_ + c) * 40 + j;
        S = fmaf(sPart[o], sc_, S);
        O = fmaf(oPart[o * 32 + d], sc_, O);
    }
    attnOut[((size_t)b * 40 + j) * 256 + h * 32 + d] = O / S;
}

// ---------------------------------------------------------------------------
// Final-projection GEMM (R1-proven): M=160, N=256, K=256 fp32 VALU.
// Grid (10,4) x 256 threads. X tile in LDS (broadcast, conflict-free).
// ---------------------------------------------------------------------------
__global__ __launch_bounds__(256) void gemm_out(const float* __restrict__ X,
                                                const float* __restrict__ Wc,
                                                const float* __restrict__ bias,
                                                float* __restrict__ Y) {
    const int t = threadIdx.x;
    const int rowBase = blockIdx.x * 16;   // 160 = 10*16 exact
    const int colBase = blockIdx.y * 64;
    const int col = colBase + (t & 63);
    const int rq = (t >> 6) * 4;           // rows rq..rq+3 of the tile

    __shared__ float Xs[16][256];
#pragma unroll
    for (int e = t; e < 1024; e += 256) {
        const int r = e >> 6, kq = (e & 63) * 4;
        *(float4*)&Xs[r][kq] = *(const float4*)(X + (size_t)(rowBase + r) * 256 + kq);
    }
    __syncthreads();

    const float* wr = Wc + (size_t)col * 256;
    float acc[4] = {0.f, 0.f, 0.f, 0.f};
#pragma unroll 8
    for (int k = 0; k < 256; k += 4) {
        const float4 wv = *(const float4*)(wr + k);
#pragma unroll
        for (int r = 0; r < 4; ++r) {
            acc[r] = fmaf(Xs[rq + r][k + 0], wv.x, acc[r]);
            acc[r] = fmaf(Xs[rq + r][k + 1], wv.y, acc[r]);
            acc[r] = fmaf(Xs[rq + r][k + 2], wv.z, acc[r]);
            acc[r] = fmaf(Xs[rq + r][k + 3], wv.w, acc[r]);
        }
    }

    const float bv = bias[col];
#pragma unroll
    for (int r = 0; r < 4; ++r)
        Y[(size_t)(rowBase + rq + r) * 256 + col] = acc[r] + bv;
}

// ---------------------------------------------------------------------------
extern "C" void kernel_launch(void* const* d_in, const int* in_sizes, int n_in,
                              void* d_out, int out_size, void* d_ws, size_t ws_size,
                              hipStream_t stream) {
    const float* q  = (const float*)d_in[0];
    const float* k  = (const float*)d_in[1];
    const float* v  = (const float*)d_in[2];
    const float* Wq = (const float*)d_in[3];
    const float* bq = (const float*)d_in[4];
    const float* Wk = (const float*)d_in[5];
    const float* bk = (const float*)d_in[6];
    const float* Wv = (const float*)d_in[7];
    const float* bv = (const float*)d_in[8];
    const float* Wc = (const float*)d_in[9];
    const float* bc = (const float*)d_in[10];
    const int* idx  = (const int*)d_in[11];
    float* out = (float*)d_out;

    // Workspace map (peak ~42 MB):
    //  [0,8)MB qp | [8,16) kp | [16,24) vp
    //  [24,28) Khi; later mPart/sPart/oPart (attn partials, 2.8 MB)
    //  [28,32) Klo
    //  32M+0 Mv(256K) | +256K Qmean(256K) | +512K Ksum32(128K)
    //  +640K candIdx(8K) | +656K refPart(64K) | +720K attnOut(160K)
    //  40M Whs(384K) | 40M+512K Wms(384K) | 41M Wls(384K)
    char* w = (char*)d_ws;
    float*          qp      = (float*)(w);
    float*          kp      = (float*)(w + (8u << 20));
    float*          vp      = (float*)(w + (16u << 20));
    unsigned short* Khi     = (unsigned short*)(w + (24u << 20));
    unsigned short* Klo     = (unsigned short*)(w + (28u << 20));
    float*          Mv      = (float*)(w + (32u << 20));
    float*          Qmean   = (float*)(w + (32u << 20) + (256u << 10));
    float*          Ksum32  = (float*)(w + (32u << 20) + (512u << 10));
    int*            candIdx = (int*)  (w + (32u << 20) + (640u << 10));
    float*          refPart = (float*)(w + (32u << 20) + (656u << 10));
    float*          attnOut = (float*)(w + (32u << 20) + (720u << 10));
    unsigned short* Whs     = (unsigned short*)(w + (40u << 20));
    unsigned short* Wms     = (unsigned short*)(w + (40u << 20) + (512u << 10));
    unsigned short* Wls     = (unsigned short*)(w + (41u << 20));
    float*          mPart   = (float*)(w + (24u << 20));                // after mpart_mfma
    float*          sPart   = (float*)(w + (24u << 20) + (128u << 10));
    float*          oPart   = (float*)(w + (24u << 20) + (256u << 10)); // 2.62 MB

    // 9 launches.
    hipLaunchKernelGGL(wsplit, dim3(192), dim3(256), 0, stream, Wq, Wk, Wv, Whs, Wms, Wls);
    hipLaunchKernelGGL(gemm_proj, dim3(128, 2, 3), dim3(256), 0, stream,
                       q, k, v, Whs, Wms, Wls, bq, bk, bv, qp, kp, vp);
    hipLaunchKernelGGL(kconv_ksum, dim3(1024), dim3(256), 0, stream, kp, idx, Khi, Klo, Ksum32);
    hipLaunchKernelGGL(mpart_mfma, dim3(1024), dim3(256), 0, stream, qp, Khi, Klo, Ksum32, Mv, Qmean);
    hipLaunchKernelGGL(topk64_fast, dim3(32), dim3(256), 0, stream, Mv, candIdx);
    hipLaunchKernelGGL(refine_kernel, dim3(256), dim3(256), 0, stream, qp, kp, idx, candIdx, refPart);
    hipLaunchKernelGGL(attn_part, dim3(512), dim3(320), 0, stream,
                       qp, kp, vp, candIdx, refPart, Qmean, mPart, sPart, oPart);
    hipLaunchKernelGGL(attn_combine, dim3(160), dim3(256), 0, stream, mPart, sPart, oPart, attnOut);
    hipLaunchKernelGGL(gemm_out, dim3(10, 4), dim3(256), 0, stream, attnOut, Wc, bc, out);
}